// Round 7
// baseline (252.789 us; speedup 1.0000x reference)
//
#include <hip/hip_runtime.h>

// x (64,32,4096) fp32; emb (1024,256) fp32.
// Row n = bl*16 + v (bl = b*32+l); z_flat[n][a] = x[bl*4096 + a*16 + v].
// Outputs FLOAT32, concat: z_q [8388608] (b,l,a,v), decoder_input [8388608]
// (== z_q forward), tokens [32768] (b,l,v).
//
// Strategy: fp16 MFMA coarse scoring (esq - 2*dot, zsq dropped: per-row
// constant), tracking coarse TOP-3 per row. Certification by TAU_C = 3e-4:
//   V2-V1 > TAU          -> coarse I1 is exact-certified
//   V2-V1 <= TAU < V3-V1 -> true argmin in {I1,I2}: exact-rescore 2 cands
//   V3-V1 <= TAU         -> full 1024-cand exact rescan, candidate-parallel
// Round N+7: rounds N+5/N+6 crashed from a macro-shadowing UB bug:
// COMPUTE_CHUNK declared `const int c = (c0) + ln;` while being invoked with
// c0 = `c * 16` -- in C++ the initializer sees the NEW (uninitialized) `c`,
// not the loop counter -> garbage candidate index -> OOB esq/emb reads ->
// GPU memory fault. Fixed by renaming (macro-local `cand`, loop var `ch`).
// Design unchanged from N+5: barrier-free/LDS-free scorer, each wave owns
// 16 rows x all 1024 cands, B-fragments are contiguous 16B loads from eht
// (L2-resident), register double-buffered (bA/bB), finalize fused into the
// wave epilogue, atomic list indices clamped (OOB-proof under any replay).
// Exact path numerics identical to the passing kernel's phase 3: f64 dots,
// f32 outer emulation, first-index tie-break.

#define A_DIM 256
#define VOCAB 1024
#define NROWS 32768
#define ZQ_ELEMS ((size_t)8388608)
#define TAU_C 3.0e-4f
#define TAU_F 2.0e-4f

typedef _Float16 f16x8 __attribute__((ext_vector_type(8)));
typedef float f32x4 __attribute__((ext_vector_type(4)));

// ---- ws layout (bytes) ----
#define WS_EHT   ((size_t)0)         // _Float16 [32][1024][8]  = 524288
#define WS_ZH    ((size_t)524288)    // _Float16 [32768][256]   = 16777216
#define WS_ESQ   ((size_t)17301504)  // float [1024]            = 4096
#define WS_ZSQ   ((size_t)17305600)  // float [32768]           = 131072
#define WS_TOK   ((size_t)17436672)  // int [32768]             = 131072
#define WS_PLIST ((size_t)17567744)  // int4 [32768]            = 524288
#define WS_FLIST ((size_t)18092032)  // int [32768]             = 131072
#define WS_CNT   ((size_t)18223104)  // int[2] (pad 128)
#define WS_NEED  ((size_t)18223232)

// ================= fast path =================

// esq (np-f32-emulated) + eh_t fp16 in [k/8][cand][8] layout; zero counters
__global__ __launch_bounds__(256) void prep_e_kernel(const float* __restrict__ emb,
                                                     float* __restrict__ esq,
                                                     _Float16* __restrict__ eht,
                                                     int* __restrict__ cnt) {
    int j = blockIdx.x * 256 + threadIdx.x;
    if (blockIdx.x == 0 && threadIdx.x < 2) cnt[threadIdx.x] = 0;
    if (j >= VOCAB) return;
    const float4* row = (const float4*)(emb + (size_t)j * A_DIM);
    double s = 0.0;
    #pragma unroll 4
    for (int t = 0; t < A_DIM / 4; ++t) {
        float4 f = row[t];
        float sx = f.x * f.x, sy = f.y * f.y, sz = f.z * f.z, sw = f.w * f.w;
        s += (double)sx + (double)sy + (double)sz + (double)sw;
    }
    esq[j] = (float)s;
    #pragma unroll 4
    for (int kb = 0; kb < 32; ++kb) {
        float4 e0 = row[kb * 2], e1 = row[kb * 2 + 1];
        f16x8 h;
        h[0] = (_Float16)e0.x; h[1] = (_Float16)e0.y; h[2] = (_Float16)e0.z; h[3] = (_Float16)e0.w;
        h[4] = (_Float16)e1.x; h[5] = (_Float16)e1.y; h[6] = (_Float16)e1.z; h[7] = (_Float16)e1.w;
        *(f16x8*)(eht + ((size_t)kb * 1024 + j) * 8) = h;
    }
}

// zh fp16 [row][k] (transposed from x) + zsq (f64 sum of f32 squares -> f32)
__global__ __launch_bounds__(256) void prep_z_kernel(const float* __restrict__ x,
                                                     _Float16* __restrict__ zh,
                                                     float* __restrict__ zsq) {
    __shared__ float raw[A_DIM * 17];  // [a*17 + v], padded to kill conflicts
    const int tid = threadIdx.x;
    const int bl = blockIdx.x;         // 0..2047
    #pragma unroll
    for (int t = 0; t < 4; ++t) {
        int f4 = tid * 4 + t * 1024;   // = a*16 + v0, v0 multiple of 4
        float4 val = *(const float4*)(x + (size_t)bl * 4096 + f4);
        int a = f4 >> 4, v0 = f4 & 15;
        raw[a * 17 + v0 + 0] = val.x;
        raw[a * 17 + v0 + 1] = val.y;
        raw[a * 17 + v0 + 2] = val.z;
        raw[a * 17 + v0 + 3] = val.w;
    }
    __syncthreads();
    #pragma unroll
    for (int t = 0; t < 16; ++t) {
        int f = tid + t * 256;
        int v = f >> 8, a = f & 255;
        zh[((size_t)bl * 16 + v) * 256 + a] = (_Float16)raw[a * 17 + v];
    }
    if (tid < 16) {
        double s = 0.0;
        for (int a = 0; a < A_DIM; ++a) {
            float zf = raw[a * 17 + tid];
            float z2 = zf * zf;            // np squares in f32
            s += (double)z2;
        }
        zsq[bl * 16 + tid] = (float)s;
    }
}

// MFMA coarse scorer v5b: barrier-free, LDS-free. Block = 64 rows (4 waves x
// 16 rows); each wave scans ALL 1024 cands in 64 chunks of 16, B-fragments
// loaded straight from eht (contiguous 16B/lane, L2/L3-resident), register
// double-buffered. Epilogue: 16-lane butterfly top-3 merge, then the wave
// writes tok + token-output and classifies near-ties (finalize fused).
__global__ __launch_bounds__(256, 2) void mfma_kernel(const _Float16* __restrict__ zh,
                                                      const _Float16* __restrict__ eht,
                                                      const float* __restrict__ esq_g,
                                                      int* __restrict__ tok,
                                                      int4* __restrict__ plist,
                                                      int* __restrict__ flist,
                                                      int* __restrict__ cnt,
                                                      float* __restrict__ out) {
    const int tid = threadIdx.x;
    const int w = tid >> 6;            // wave 0..3
    const int lane = tid & 63;
    const int q = lane >> 4;           // quad
    const int ln = lane & 15;
    const int row0 = blockIdx.x * 64 + w * 16;

    // A-fragment register cache: 1 M-tile x 8 k-steps
    f16x8 afr[8];
    #pragma unroll
    for (int kt = 0; kt < 8; ++kt)
        afr[kt] = *(const f16x8*)(zh + (size_t)(row0 + ln) * 256 + kt * 32 + q * 8);

    float tv1[4], tv2[4], tv3[4];
    int   ti1[4], ti2[4], ti3[4];
    #pragma unroll
    for (int s = 0; s < 4; ++s) {
        tv1[s] = 3.0e38f; tv2[s] = 3.0e38f; tv3[s] = 3.0e38f;
        ti1[s] = 0; ti2[s] = 0; ti3[s] = 0;
    }

    // chunk = 16 cands. B-fragment for (kb=kt*4+q, cand c): eht[kb][c][0..7],
    // one contiguous 16B load per lane (quad reads 256B contiguous).
    // NOTE: macro-locals use names (cand) disjoint from all caller variables
    // -- the N+5 crash was `const int c = (c0)+ln;` shadowing the loop's c.
    #define LOAD_CHUNK(c0, bfr)                                                          \
        {                                                                                \
            _Pragma("unroll")                                                            \
            for (int kt = 0; kt < 8; ++kt)                                               \
                bfr[kt] = *(const f16x8*)(eht +                                          \
                    ((size_t)(kt * 4 + q) * 1024 + (c0) + ln) * 8);                      \
        }

    #define COMPUTE_CHUNK(c0, bfr)                                                       \
        {                                                                                \
            f32x4 acc = (f32x4){0.f, 0.f, 0.f, 0.f};                                     \
            _Pragma("unroll")                                                            \
            for (int kt = 0; kt < 8; ++kt)                                               \
                acc = __builtin_amdgcn_mfma_f32_16x16x32_f16(afr[kt], bfr[kt], acc,      \
                                                             0, 0, 0);                   \
            const int cand = (c0) + ln;                                                  \
            float es = esq_g[cand];                                                      \
            _Pragma("unroll")                                                            \
            for (int reg = 0; reg < 4; ++reg) {                                          \
                float s = fmaf(-2.0f, acc[reg], es);                                     \
                if (s < tv3[reg]) {                                                      \
                    if (s < tv2[reg]) {                                                  \
                        tv3[reg] = tv2[reg]; ti3[reg] = ti2[reg];                        \
                        if (s < tv1[reg]) {                                              \
                            tv2[reg] = tv1[reg]; ti2[reg] = ti1[reg];                    \
                            tv1[reg] = s; ti1[reg] = cand;                               \
                        } else { tv2[reg] = s; ti2[reg] = cand; }                        \
                    } else { tv3[reg] = s; ti3[reg] = cand; }                            \
                }                                                                        \
            }                                                                            \
        }

    f16x8 bA[8], bB[8];
    LOAD_CHUNK(0, bA)
    for (int ch = 0; ch < 64; ch += 2) {
        LOAD_CHUNK((ch + 1) * 16, bB)
        COMPUTE_CHUNK(ch * 16, bA)
        if (ch + 2 < 64) LOAD_CHUNK((ch + 2) * 16, bA)
        COMPUTE_CHUNK((ch + 1) * 16, bB)
    }
    #undef LOAD_CHUNK
    #undef COMPUTE_CHUNK

    // butterfly top-3 merge across the 16 lanes of each quad, then fused
    // finalize: write tokens + classify near-ties.
    #pragma unroll
    for (int slot = 0; slot < 4; ++slot) {
        float v1 = tv1[slot], v2 = tv2[slot], v3 = tv3[slot];
        int i1 = ti1[slot], i2 = ti2[slot], i3 = ti3[slot];
        #pragma unroll
        for (int m = 1; m <= 8; m <<= 1) {
            float ov1 = __shfl_xor(v1, m); int oi1 = __shfl_xor(i1, m);
            float ov2 = __shfl_xor(v2, m); int oi2 = __shfl_xor(i2, m);
            float ov3 = __shfl_xor(v3, m); int oi3 = __shfl_xor(i3, m);
            #define INS3(ov, oi)                                                         \
                if (ov < v3 || (ov == v3 && oi < i3)) {                                  \
                    if (ov < v2 || (ov == v2 && oi < i2)) {                              \
                        v3 = v2; i3 = i2;                                                \
                        if (ov < v1 || (ov == v1 && oi < i1)) {                          \
                            v2 = v1; i2 = i1; v1 = ov; i1 = oi;                          \
                        } else { v2 = ov; i2 = oi; }                                     \
                    } else { v3 = ov; i3 = oi; }                                         \
                }
            INS3(ov1, oi1)
            INS3(ov2, oi2)
            INS3(ov3, oi3)
            #undef INS3
        }
        if (ln == 0) {
            int row = row0 + q * 4 + slot;
            tok[row] = i1;
            out[2 * ZQ_ELEMS + (size_t)row] = (float)i1;
            if (v2 - v1 <= TAU_C) {
                if (v3 - v1 > TAU_C) {
                    int p = atomicAdd(&cnt[0], 1) & (NROWS - 1);  // clamp: OOB-proof
                    plist[p] = make_int4(row, i1, i2, 0);
                } else {
                    int p = atomicAdd(&cnt[1], 1) & (NROWS - 1);  // clamp: OOB-proof
                    flist[p] = row;
                }
            }
        }
    }
}

// merged exact rescan.
// Phase A (pair items, one per wave, grid-strided): exact 2-candidate
// rescore, lanes split the 256-dim f64 dot, butterfly-reduce.
// Phase B (full items, one ROW per BLOCK): candidate-parallel — each of the
// 256 threads owns 4 consecutive emb rows and runs 4 interleaved f64 FMA
// chains; one f32 (val,idx) butterfly + 4-entry merge at the end. f64 dots,
// f32 outer emulation, first-index tie-break everywhere.
__global__ __launch_bounds__(256) void rescan2_kernel(const float* __restrict__ x,
                                                      const float* __restrict__ emb,
                                                      const float* __restrict__ esq,
                                                      const float* __restrict__ zsq,
                                                      int* __restrict__ tok,
                                                      const int4* __restrict__ plist,
                                                      const int* __restrict__ flist,
                                                      const int* __restrict__ cnt,
                                                      float* __restrict__ out) {
    __shared__ float zrow[A_DIM];
    __shared__ float wv[4];
    __shared__ int   wi[4];
    const int tid = threadIdx.x;
    const int w = tid >> 6, lane = tid & 63;

    // ---- phase A: pair items ----
    {
        const int nw = gridDim.x * 4;
        const int gw = blockIdx.x * 4 + w;
        const int np = min(cnt[0], NROWS);   // clamp: OOB-proof
        for (int i = gw; i < np; i += nw) {
            int4 e = plist[i];
            const int r = e.x, c1 = e.y, c2 = e.z;
            const float* xr = x + (size_t)(r >> 4) * 4096 + (r & 15);
            const float* e1 = emb + (size_t)c1 * A_DIM;
            const float* e2 = emb + (size_t)c2 * A_DIM;
            double d1 = 0.0, d2 = 0.0;
            #pragma unroll
            for (int k = 0; k < 4; ++k) {
                int a = lane + k * 64;
                double zv = (double)xr[a * 16];
                d1 = fma(zv, (double)e1[a], d1);
                d2 = fma(zv, (double)e2[a], d2);
            }
            #pragma unroll
            for (int m = 1; m < 64; m <<= 1) {
                d1 += __shfl_xor(d1, m);
                d2 += __shfl_xor(d2, m);
            }
            if (lane == 0) {
                float zq = zsq[r];
                float A1 = zq + esq[c1];
                float D1 = (float)(2.0 * d1);
                float s1 = A1 - D1;
                float A2 = zq + esq[c2];
                float D2 = (float)(2.0 * d2);
                float s2 = A2 - D2;
                int bi = (s2 < s1 || (s2 == s1 && c2 < c1)) ? c2 : c1;
                tok[r] = bi;
                out[2 * ZQ_ELEMS + (size_t)r] = (float)bi;
            }
        }
    }

    // ---- phase B: full rows, candidate-parallel ----
    const int nf = min(cnt[1], NROWS);       // clamp: OOB-proof
    for (int i = blockIdx.x; i < nf; i += gridDim.x) {
        const int r = flist[i];
        __syncthreads();   // previous iteration's zrow readers done
        zrow[tid] = x[(size_t)(r >> 4) * 4096 + (size_t)tid * 16 + (r & 15)];
        __syncthreads();

        // thread tid owns candidates 4*tid .. 4*tid+3 (contiguous emb rows)
        const float4* e0 = (const float4*)(emb + (size_t)tid * 4 * A_DIM);
        double d0 = 0.0, d1 = 0.0, d2 = 0.0, d3 = 0.0;
        #pragma unroll 8
        for (int k4 = 0; k4 < A_DIM / 4; ++k4) {
            float4 zf = *(const float4*)&zrow[k4 * 4];   // LDS broadcast
            double z0 = (double)zf.x, z1 = (double)zf.y;
            double z2 = (double)zf.z, z3 = (double)zf.w;
            float4 f0 = e0[k4];
            float4 f1 = e0[64 + k4];
            float4 f2 = e0[128 + k4];
            float4 f3 = e0[192 + k4];
            d0 = fma((double)f0.x, z0, d0); d0 = fma((double)f0.y, z1, d0);
            d0 = fma((double)f0.z, z2, d0); d0 = fma((double)f0.w, z3, d0);
            d1 = fma((double)f1.x, z0, d1); d1 = fma((double)f1.y, z1, d1);
            d1 = fma((double)f1.z, z2, d1); d1 = fma((double)f1.w, z3, d1);
            d2 = fma((double)f2.x, z0, d2); d2 = fma((double)f2.y, z1, d2);
            d2 = fma((double)f2.z, z2, d2); d2 = fma((double)f2.w, z3, d2);
            d3 = fma((double)f3.x, z0, d3); d3 = fma((double)f3.y, z1, d3);
            d3 = fma((double)f3.z, z2, d3); d3 = fma((double)f3.w, z3, d3);
        }
        const float zq = zsq[r];
        float bv = 3.0e38f; int bi = 0;
        double dd[4] = {d0, d1, d2, d3};
        #pragma unroll
        for (int cc = 0; cc < 4; ++cc) {               // ascending c
            int c = tid * 4 + cc;
            float A = zq + esq[c];                     // fl32(zsq + esq)
            float D = (float)(2.0 * dd[cc]);           // fl32(2*dot)
            float s = A - D;                           // fl32(A - D)
            if (s < bv) { bv = s; bi = c; }            // strict < -> first index
        }
        // wave butterfly on (bv,bi), explicit first-index tie-break
        #pragma unroll
        for (int m = 1; m < 64; m <<= 1) {
            float ov = __shfl_xor(bv, m); int oi = __shfl_xor(bi, m);
            if (ov < bv || (ov == bv && oi < bi)) { bv = ov; bi = oi; }
        }
        if (lane == 0) { wv[w] = bv; wi[w] = bi; }
        __syncthreads();
        if (tid == 0) {
            float BV = wv[0]; int BI = wi[0];
            #pragma unroll
            for (int t = 1; t < 4; ++t)
                if (wv[t] < BV || (wv[t] == BV && wi[t] < BI)) { BV = wv[t]; BI = wi[t]; }
            tok[r] = BI;
            out[2 * ZQ_ELEMS + (size_t)r] = (float)BI;
        }
    }
}

// gather epilogue: z_q + decoder_input
__global__ __launch_bounds__(256) void gather_kernel(const float* __restrict__ emb,
                                                     const int* __restrict__ tok,
                                                     float* __restrict__ out) {
    __shared__ int t16[16];
    const int tid = threadIdx.x;
    const int bl = blockIdx.x;
    if (tid < 16) t16[tid] = tok[bl * 16 + tid];
    __syncthreads();
    const int a = tid;
    __align__(16) float h[16];
    #pragma unroll
    for (int v = 0; v < 16; ++v) h[v] = emb[(size_t)t16[v] * A_DIM + a];
    size_t base = ((size_t)bl * A_DIM + a) * 16;
    float4* p0 = (float4*)(out + base);
    float4* p1 = (float4*)(out + ZQ_ELEMS + base);
    #pragma unroll
    for (int qq = 0; qq < 4; ++qq) {
        float4 val = *(float4*)&h[qq * 4];
        p0[qq] = val;
        p1[qq] = val;
    }
}

// ================= fallback path (round-5 PASSING kernel, verbatim) =================

__global__ __launch_bounds__(256) void prep_f(const float* __restrict__ emb,
                                              float* __restrict__ e_sq32) {
    int j = blockIdx.x * 256 + threadIdx.x;
    if (j < VOCAB) {
        const float4* row = (const float4*)(emb + (size_t)j * A_DIM);
        double s = 0.0;
        #pragma unroll 4
        for (int t = 0; t < A_DIM / 4; ++t) {
            float4 f = row[t];
            float sx = f.x * f.x, sy = f.y * f.y, sz = f.z * f.z, sw = f.w * f.w;
            s += (double)sx + (double)sy + (double)sz + (double)sw;
        }
        e_sq32[j] = (float)s;
    }
}

#define FBM 64
#define FBN 256
#define FBK 32
struct SmemF {
    union {
        struct { float zs[FBK][FBM]; float es[FBK][FBN]; };
        float4 mbuf[FBM][32];
        struct { double zrow[A_DIM]; float rbest[256]; int ridx[256]; };
    };
    double zsqp_s[4][FBM];
    float  zsq[FBM];
    int    tok[FBM];
    int    flagrows[FBM];
    int    nflag;
};

__global__ __launch_bounds__(256, 2) void main_f(const float* __restrict__ x,
                                                 const float* __restrict__ emb,
                                                 const float* __restrict__ e_sq32,
                                                 float* __restrict__ out) {
    __shared__ SmemF sm;
    const int tid = threadIdx.x;
    const int tx = tid & 31;
    const int ty = tid >> 5;
    const int blk = blockIdx.x;
    const int row0 = blk * FBM;
    const int bl0 = row0 >> 4;
    const int zrow_id = tid & 63;
    const int zq4     = tid >> 6;

    if (tid == 0) sm.nflag = 0;
    float v1[8], v2[8];
    int   i1[8], i2[8];
    #pragma unroll
    for (int r = 0; r < 8; ++r) { v1[r] = 3.0e38f; v2[r] = 3.0e38f; i1[r] = 0; i2[r] = 0; }
    double zsqp = 0.0;
    float4 zpf[2];
    float4 epf[8];
    for (int ct = 0; ct < VOCAB / FBN; ++ct) {
        float acc[8][8];
        #pragma unroll
        for (int rr = 0; rr < 8; ++rr)
            #pragma unroll
            for (int cc = 0; cc < 8; ++cc) acc[rr][cc] = 0.0f;
        for (int kt = 0; kt < A_DIM / FBK; ++kt) {
            if (kt == 0) {
                #pragma unroll
                for (int t = 0; t < 2; ++t) {
                    int f = tid + t * 256;
                    int v4 = f & 3, g = (f >> 2) & 3, kk = f >> 4;
                    zpf[t] = *(const float4*)(x + (size_t)(bl0 + g) * 4096 + (kt * FBK + kk) * 16 + v4 * 4);
                }
                #pragma unroll
                for (int t = 0; t < 8; ++t) {
                    int f = tid + t * 256;
                    int c = f & 255, k4 = f >> 8;
                    epf[t] = *(const float4*)(emb + (size_t)(ct * FBN + c) * A_DIM + kt * FBK + k4 * 4);
                }
            }
            __syncthreads();
            #pragma unroll
            for (int t = 0; t < 2; ++t) {
                int f = tid + t * 256;
                int v4 = f & 3, g = (f >> 2) & 3, kk = f >> 4;
                *(float4*)&sm.zs[kk][g * 16 + v4 * 4] = zpf[t];
            }
            #pragma unroll
            for (int t = 0; t < 8; ++t) {
                int f = tid + t * 256;
                int c = f & 255, k4 = f >> 8;
                sm.es[k4 * 4 + 0][c] = epf[t].x;
                sm.es[k4 * 4 + 1][c] = epf[t].y;
                sm.es[k4 * 4 + 2][c] = epf[t].z;
                sm.es[k4 * 4 + 3][c] = epf[t].w;
            }
            __syncthreads();
            if (kt + 1 < A_DIM / FBK) {
                #pragma unroll
                for (int t = 0; t < 2; ++t) {
                    int f = tid + t * 256;
                    int v4 = f & 3, g = (f >> 2) & 3, kk = f >> 4;
                    zpf[t] = *(const float4*)(x + (size_t)(bl0 + g) * 4096 + ((kt + 1) * FBK + kk) * 16 + v4 * 4);
                }
                #pragma unroll
                for (int t = 0; t < 8; ++t) {
                    int f = tid + t * 256;
                    int c = f & 255, k4 = f >> 8;
                    epf[t] = *(const float4*)(emb + (size_t)(ct * FBN + c) * A_DIM + (kt + 1) * FBK + k4 * 4);
                }
            }
            if (ct == 0 && (kt >> 1) == zq4) {
                #pragma unroll
                for (int kk = 0; kk < FBK; ++kk) {
                    float zf = sm.zs[kk][zrow_id];
                    float zf2 = zf * zf;
                    zsqp += (double)zf2;
                }
            }
            #pragma unroll 2
            for (int kk = 0; kk < FBK; ++kk) {
                float4 za = *(float4*)&sm.zs[kk][ty * 4];
                float4 zb = *(float4*)&sm.zs[kk][32 + ty * 4];
                float4 ea = *(float4*)&sm.es[kk][tx * 4];
                float4 eb = *(float4*)&sm.es[kk][128 + tx * 4];
                float zv[8] = {za.x, za.y, za.z, za.w, zb.x, zb.y, zb.z, zb.w};
                float ev[8] = {ea.x, ea.y, ea.z, ea.w, eb.x, eb.y, eb.z, eb.w};
                #pragma unroll
                for (int rr = 0; rr < 8; ++rr)
                    #pragma unroll
                    for (int cc = 0; cc < 8; ++cc)
                        acc[rr][cc] = fmaf(zv[rr], ev[cc], acc[rr][cc]);
            }
        }
        if (ct == 0) {
            sm.zsqp_s[zq4][zrow_id] = zsqp;
            __syncthreads();
            if (tid < FBM)
                sm.zsq[tid] = (float)(sm.zsqp_s[0][tid] + sm.zsqp_s[1][tid]
                                    + sm.zsqp_s[2][tid] + sm.zsqp_s[3][tid]);
            __syncthreads();
        }
        float esqv[8];
        #pragma unroll
        for (int cc = 0; cc < 8; ++cc) {
            int c = ct * FBN + (cc >> 2) * 128 + tx * 4 + (cc & 3);
            esqv[cc] = e_sq32[c];
        }
        #pragma unroll
        for (int rr = 0; rr < 8; ++rr) {
            int R = (rr >> 2) * 32 + ty * 4 + (rr & 3);
            float zq = sm.zsq[R];
            #pragma unroll
            for (int cc = 0; cc < 8; ++cc) {
                int c = ct * FBN + (cc >> 2) * 128 + tx * 4 + (cc & 3);
                float A = zq + esqv[cc];
                float s = fmaf(-2.0f, acc[rr][cc], A);
                if (s < v1[rr]) { v2[rr] = v1[rr]; i2[rr] = i1[rr]; v1[rr] = s; i1[rr] = c; }
                else if (s < v2[rr]) { v2[rr] = s; i2[rr] = c; }
            }
        }
    }
    __syncthreads();
    #pragma unroll
    for (int rr = 0; rr < 8; ++rr) {
        int r = (rr >> 2) * 32 + ty * 4 + (rr & 3);
        float4 m;
        m.x = v1[rr]; m.y = __int_as_float(i1[rr]);
        m.z = v2[rr]; m.w = __int_as_float(i2[rr]);
        sm.mbuf[r][tx] = m;
    }
    __syncthreads();
    if (tid < FBM) {
        int r = tid;
        float V1 = 3.0e38f, V2 = 3.0e38f;
        int I1 = 0, I2 = 0;
        for (int t = 0; t < 32; ++t) {
            float4 m = sm.mbuf[r][t];
            float a1 = m.x; int a1i = __float_as_int(m.y);
            float a2 = m.z; int a2i = __float_as_int(m.w);
            if (a1 < V1 || (a1 == V1 && a1i < I1)) { V2 = V1; I2 = I1; V1 = a1; I1 = a1i; }
            else if (a1 < V2 || (a1 == V2 && a1i < I2)) { V2 = a1; I2 = a1i; }
            if (a2 < V1 || (a2 == V1 && a2i < I1)) { V2 = V1; I2 = I1; V1 = a2; I1 = a2i; }
            else if (a2 < V2 || (a2 == V2 && a2i < I2)) { V2 = a2; I2 = a2i; }
        }
        sm.tok[r] = I1;
        if (V2 - V1 <= TAU_F) {
            int pos = atomicAdd(&sm.nflag, 1);
            sm.flagrows[pos] = r;
        }
    }
    __syncthreads();
    const int nf = sm.nflag;
    for (int i = 0; i < nf; ++i) {
        const int rl = sm.flagrows[i];
        const int bl = bl0 + (rl >> 4);
        const int v  = rl & 15;
        const float zqrow = sm.zsq[rl];
        sm.zrow[tid] = (double)x[(size_t)bl * 4096 + (size_t)tid * 16 + v];
        __syncthreads();
        float bv = 3.0e38f; int bi = 0;
        #pragma unroll
        for (int cc = 0; cc < 4; ++cc) {
            int c = tid * 4 + cc;
            const float4* er = (const float4*)(emb + (size_t)c * A_DIM);
            double dot = 0.0;
            #pragma unroll 8
            for (int k4 = 0; k4 < A_DIM / 4; ++k4) {
                float4 f = er[k4];
                dot = fma((double)f.x, sm.zrow[k4 * 4 + 0], dot);
                dot = fma((double)f.y, sm.zrow[k4 * 4 + 1], dot);
                dot = fma((double)f.z, sm.zrow[k4 * 4 + 2], dot);
                dot = fma((double)f.w, sm.zrow[k4 * 4 + 3], dot);
            }
            float A = zqrow + e_sq32[c];
            float D = (float)(2.0 * dot);
            float s = A - D;
            if (s < bv) { bv = s; bi = c; }
        }
        sm.rbest[tid] = bv; sm.ridx[tid] = bi;
        __syncthreads();
        if (tid == 0) {
            float BV = sm.rbest[0]; int BI = sm.ridx[0];
            for (int t = 1; t < 256; ++t) {
                float vv = sm.rbest[t];
                if (vv < BV) { BV = vv; BI = sm.ridx[t]; }
            }
            sm.tok[rl] = BI;
        }
        __syncthreads();
    }
    if (tid < FBM) {
        out[2 * ZQ_ELEMS + (size_t)(row0 + tid)] = (float)sm.tok[tid];
    }
    __syncthreads();
    const int a = tid;
    for (int g = 0; g < 4; ++g) {
        __align__(16) float h[16];
        #pragma unroll
        for (int v = 0; v < 16; ++v) {
            h[v] = emb[(size_t)sm.tok[g * 16 + v] * A_DIM + a];
        }
        size_t base = ((size_t)(bl0 + g) * A_DIM + a) * 16;
        float4* p0 = (float4*)(out + base);
        float4* p1 = (float4*)(out + ZQ_ELEMS + base);
        #pragma unroll
        for (int qq = 0; qq < 4; ++qq) {
            float4 val = *(float4*)&h[qq * 4];
            p0[qq] = val;
            p1[qq] = val;
        }
    }
}

extern "C" void kernel_launch(void* const* d_in, const int* in_sizes, int n_in,
                              void* d_out, int out_size, void* d_ws, size_t ws_size,
                              hipStream_t stream) {
    (void)in_sizes; (void)n_in; (void)out_size;
    const float* x   = (const float*)d_in[0];
    const float* emb = (const float*)d_in[1];
    float* out = (float*)d_out;
    char* ws = (char*)d_ws;

    if (ws_size >= WS_NEED) {
        _Float16* eht = (_Float16*)(ws + WS_EHT);
        _Float16* zh  = (_Float16*)(ws + WS_ZH);
        float* esq    = (float*)(ws + WS_ESQ);
        float* zsq    = (float*)(ws + WS_ZSQ);
        int* tok      = (int*)(ws + WS_TOK);
        int4* plist   = (int4*)(ws + WS_PLIST);
        int* flist    = (int*)(ws + WS_FLIST);
        int* cnt      = (int*)(ws + WS_CNT);

        prep_e_kernel<<<4, 256, 0, stream>>>(emb, esq, eht, cnt);
        prep_z_kernel<<<2048, 256, 0, stream>>>(x, zh, zsq);
        mfma_kernel<<<512, 256, 0, stream>>>(zh, eht, esq, tok, plist, flist, cnt, out);
        rescan2_kernel<<<256, 256, 0, stream>>>(x, emb, esq, zsq, tok, plist, flist, cnt, out);
        gather_kernel<<<2048, 256, 0, stream>>>(emb, tok, out);
    } else {
        float* e_sq32 = (float*)ws;
        prep_f<<<4, 256, 0, stream>>>(emb, e_sq32);
        main_f<<<512, 256, 0, stream>>>(x, emb, e_sq32, out);
    }
}

// Round 9
// 230.830 us; speedup vs baseline: 1.0951x; 1.0951x over previous
//
#include <hip/hip_runtime.h>

// x (64,32,4096) fp32; emb (1024,256) fp32.
// Row n = bl*16 + v (bl = b*32+l); z_flat[n][a] = x[bl*4096 + a*16 + v].
// Outputs FLOAT32, concat: z_q [8388608] (b,l,a,v), decoder_input [8388608]
// (== z_q forward), tokens [32768] (b,l,v).
//
// Strategy: fp16 MFMA coarse scoring (esq - 2*dot, zsq dropped: per-row
// constant), tracking coarse TOP-3 per row. Certification by TAU_C = 3e-4:
//   V2-V1 > TAU          -> coarse I1 is exact-certified
//   V2-V1 <= TAU < V3-V1 -> true argmin in {I1,I2}: exact-rescore 2 cands
//   V3-V1 <= TAU         -> full 1024-cand exact rescan, candidate-parallel
// Round N+9: identical resubmission of round N+8 (the bench died with
// "MI355X container failed twice" -- broker infra, kernel never ran; the
// source re-audited clean). v7 ran correct at 84us: VGPR_Count=76 proved
// the compiler sank the double-buffered B loads, serializing each chunk at
// load latency with only 2 waves/SIMD (occ 18%). Fix by waves, not
// registers: block = 32 rows x 4 waves, wave (g,h) owns 16 rows x 512-cand
// HALF -> grid 1024, 2x waves, half work/wave; per-block LDS merge (1.5KB)
// of the two halves' top-3 + fused finalize. Two independent MFMA chains
// (kt 0-3 / 4-7) halve the serial chain; per-kt hoisted pointers kill the
// 64-bit addr recompute. prep_e spread 4->64 blocks (4-block grid was
// serializing 1MB through 4 CUs).
// Exact path numerics identical to the passing kernel's phase 3: f64 dots,
// f32 outer emulation, first-index tie-break.

#define A_DIM 256
#define VOCAB 1024
#define NROWS 32768
#define ZQ_ELEMS ((size_t)8388608)
#define TAU_C 3.0e-4f
#define TAU_F 2.0e-4f

typedef _Float16 f16x8 __attribute__((ext_vector_type(8)));
typedef float f32x4 __attribute__((ext_vector_type(4)));

// ---- ws layout (bytes) ----
#define WS_EHT   ((size_t)0)         // _Float16 [32][1024][8]  = 524288
#define WS_ZH    ((size_t)524288)    // _Float16 [32768][256]   = 16777216
#define WS_ESQ   ((size_t)17301504)  // float [1024]            = 4096
#define WS_ZSQ   ((size_t)17305600)  // float [32768]           = 131072
#define WS_TOK   ((size_t)17436672)  // int [32768]             = 131072
#define WS_PLIST ((size_t)17567744)  // int4 [32768]            = 524288
#define WS_FLIST ((size_t)18092032)  // int [32768]             = 131072
#define WS_CNT   ((size_t)18223104)  // int[2] (pad 128)
#define WS_NEED  ((size_t)18223232)

// ================= fast path =================

// esq (np-f32-emulated, bit-identical sequential order) + eh_t fp16 in
// [k/8][cand][8] layout; zero counters. 64 blocks x 16 rows: packing is
// 16-way kb-split across thread groups; esq by one thread per row.
__global__ __launch_bounds__(256) void prep_e_kernel(const float* __restrict__ emb,
                                                     float* __restrict__ esq,
                                                     _Float16* __restrict__ eht,
                                                     int* __restrict__ cnt) {
    const int tid = threadIdx.x;
    if (blockIdx.x == 0 && tid < 2) cnt[tid] = 0;
    const int j = blockIdx.x * 16 + (tid & 15);   // emb row 0..1023
    const int sub = tid >> 4;                      // 0..15: kb pair owner
    const float4* row = (const float4*)(emb + (size_t)j * A_DIM);
    #pragma unroll
    for (int t = 0; t < 2; ++t) {
        int kb = sub * 2 + t;                      // 0..31
        float4 e0 = row[kb * 2], e1 = row[kb * 2 + 1];
        f16x8 h;
        h[0] = (_Float16)e0.x; h[1] = (_Float16)e0.y; h[2] = (_Float16)e0.z; h[3] = (_Float16)e0.w;
        h[4] = (_Float16)e1.x; h[5] = (_Float16)e1.y; h[6] = (_Float16)e1.z; h[7] = (_Float16)e1.w;
        *(f16x8*)(eht + ((size_t)kb * 1024 + j) * 8) = h;
    }
    if (sub == 0) {
        double s = 0.0;
        #pragma unroll 4
        for (int t = 0; t < A_DIM / 4; ++t) {      // identical order to passing kernel
            float4 f = row[t];
            float sx = f.x * f.x, sy = f.y * f.y, sz = f.z * f.z, sw = f.w * f.w;
            s += (double)sx + (double)sy + (double)sz + (double)sw;
        }
        esq[j] = (float)s;
    }
}

// zh fp16 [row][k] (transposed from x) + zsq (f64 sum of f32 squares -> f32)
__global__ __launch_bounds__(256) void prep_z_kernel(const float* __restrict__ x,
                                                     _Float16* __restrict__ zh,
                                                     float* __restrict__ zsq) {
    __shared__ float raw[A_DIM * 17];  // [a*17 + v], padded to kill conflicts
    const int tid = threadIdx.x;
    const int bl = blockIdx.x;         // 0..2047
    #pragma unroll
    for (int t = 0; t < 4; ++t) {
        int f4 = tid * 4 + t * 1024;   // = a*16 + v0, v0 multiple of 4
        float4 val = *(const float4*)(x + (size_t)bl * 4096 + f4);
        int a = f4 >> 4, v0 = f4 & 15;
        raw[a * 17 + v0 + 0] = val.x;
        raw[a * 17 + v0 + 1] = val.y;
        raw[a * 17 + v0 + 2] = val.z;
        raw[a * 17 + v0 + 3] = val.w;
    }
    __syncthreads();
    #pragma unroll
    for (int t = 0; t < 16; ++t) {
        int f = tid + t * 256;
        int v = f >> 8, a = f & 255;
        zh[((size_t)bl * 16 + v) * 256 + a] = (_Float16)raw[a * 17 + v];
    }
    if (tid < 16) {
        double s = 0.0;
        for (int a = 0; a < A_DIM; ++a) {
            float zf = raw[a * 17 + tid];
            float z2 = zf * zf;            // np squares in f32
            s += (double)z2;
        }
        zsq[bl * 16 + tid] = (float)s;
    }
}

// MFMA coarse scorer v6: barrier-light, LDS only for the tiny top-3 merge.
// Block = 32 rows x 4 waves: wave (g = w&1, h = w>>1) owns 16 rows x the
// 512-cand half h; 32 chunks of 16 cands; B-fragments contiguous 16B loads
// from eht via hoisted per-kt pointers; two independent MFMA chains.
// Epilogue: per-quad butterfly top-3 -> LDS[2][32][6] -> 32-thread half
// merge + fused finalize (tok write + near-tie classification).
__global__ __launch_bounds__(256) void mfma_kernel(const _Float16* __restrict__ zh,
                                                   const _Float16* __restrict__ eht,
                                                   const float* __restrict__ esq_g,
                                                   int* __restrict__ tok,
                                                   int4* __restrict__ plist,
                                                   int* __restrict__ flist,
                                                   int* __restrict__ cnt,
                                                   float* __restrict__ out) {
    __shared__ float t3buf[2][32][6];
    const int tid = threadIdx.x;
    const int w = tid >> 6;            // wave 0..3
    const int lane = tid & 63;
    const int q = lane >> 4;           // quad
    const int ln = lane & 15;
    const int g = w & 1;               // 16-row tile within block
    const int h = w >> 1;              // candidate half
    const int row0 = blockIdx.x * 32 + g * 16;
    const int cbase = h * 512;

    // A-fragment register cache: 1 M-tile x 8 k-steps
    f16x8 afr[8];
    #pragma unroll
    for (int kt = 0; kt < 8; ++kt)
        afr[kt] = *(const f16x8*)(zh + (size_t)(row0 + ln) * 256 + kt * 32 + q * 8);

    // hoisted per-kt B pointers (statically indexed -> stay in VGPRs);
    // chunk stride = 16 cands * 16B = 256B = 16 f16x8
    const f16x8* ep[8];
    #pragma unroll
    for (int kt = 0; kt < 8; ++kt)
        ep[kt] = (const f16x8*)(eht + ((size_t)(kt * 4 + q) * 1024 + cbase + ln) * 8);

    float tv1[4], tv2[4], tv3[4];
    int   ti1[4], ti2[4], ti3[4];
    #pragma unroll
    for (int s = 0; s < 4; ++s) {
        tv1[s] = 3.0e38f; tv2[s] = 3.0e38f; tv3[s] = 3.0e38f;
        ti1[s] = 0; ti2[s] = 0; ti3[s] = 0;
    }

    for (int ch = 0; ch < 32; ++ch) {
        f16x8 bfr[8];
        #pragma unroll
        for (int kt = 0; kt < 8; ++kt)
            bfr[kt] = ep[kt][(size_t)ch * 16];
        // two independent accumulation chains (coarse-only reassociation)
        f32x4 a0 = (f32x4){0.f, 0.f, 0.f, 0.f};
        f32x4 a1 = (f32x4){0.f, 0.f, 0.f, 0.f};
        #pragma unroll
        for (int kt = 0; kt < 4; ++kt)
            a0 = __builtin_amdgcn_mfma_f32_16x16x32_f16(afr[kt], bfr[kt], a0, 0, 0, 0);
        #pragma unroll
        for (int kt = 4; kt < 8; ++kt)
            a1 = __builtin_amdgcn_mfma_f32_16x16x32_f16(afr[kt], bfr[kt], a1, 0, 0, 0);
        const int cand = cbase + ch * 16 + ln;
        float es = esq_g[cand];
        #pragma unroll
        for (int reg = 0; reg < 4; ++reg) {
            float s = fmaf(-2.0f, a0[reg] + a1[reg], es);
            if (s < tv3[reg]) {
                if (s < tv2[reg]) {
                    tv3[reg] = tv2[reg]; ti3[reg] = ti2[reg];
                    if (s < tv1[reg]) {
                        tv2[reg] = tv1[reg]; ti2[reg] = ti1[reg];
                        tv1[reg] = s; ti1[reg] = cand;
                    } else { tv2[reg] = s; ti2[reg] = cand; }
                } else { tv3[reg] = s; ti3[reg] = cand; }
            }
        }
    }

    // butterfly top-3 merge across the 16 lanes of each quad -> LDS
    #pragma unroll
    for (int slot = 0; slot < 4; ++slot) {
        float v1 = tv1[slot], v2 = tv2[slot], v3 = tv3[slot];
        int i1 = ti1[slot], i2 = ti2[slot], i3 = ti3[slot];
        #pragma unroll
        for (int m = 1; m <= 8; m <<= 1) {
            float ov1 = __shfl_xor(v1, m); int oi1 = __shfl_xor(i1, m);
            float ov2 = __shfl_xor(v2, m); int oi2 = __shfl_xor(i2, m);
            float ov3 = __shfl_xor(v3, m); int oi3 = __shfl_xor(i3, m);
            #define INS3(ov, oi)                                                         \
                if (ov < v3 || (ov == v3 && oi < i3)) {                                  \
                    if (ov < v2 || (ov == v2 && oi < i2)) {                              \
                        v3 = v2; i3 = i2;                                                \
                        if (ov < v1 || (ov == v1 && oi < i1)) {                          \
                            v2 = v1; i2 = i1; v1 = ov; i1 = oi;                          \
                        } else { v2 = ov; i2 = oi; }                                     \
                    } else { v3 = ov; i3 = oi; }                                         \
                }
            INS3(ov1, oi1)
            INS3(ov2, oi2)
            INS3(ov3, oi3)
            #undef INS3
        }
        if (ln == 0) {
            int rl = g * 16 + q * 4 + slot;
            float* hp = &t3buf[h][rl][0];
            hp[0] = v1; hp[1] = __int_as_float(i1);
            hp[2] = v2; hp[3] = __int_as_float(i2);
            hp[4] = v3; hp[5] = __int_as_float(i3);
        }
    }
    __syncthreads();

    // 32-thread half-merge + fused finalize
    if (tid < 32) {
        const float* h0 = &t3buf[0][tid][0];
        const float* h1 = &t3buf[1][tid][0];
        float v1 = h0[0]; int i1 = __float_as_int(h0[1]);
        float v2 = h0[2]; int i2 = __float_as_int(h0[3]);
        float v3 = h0[4]; int i3 = __float_as_int(h0[5]);
        #pragma unroll
        for (int e = 0; e < 3; ++e) {
            float ov = h1[2 * e]; int oi = __float_as_int(h1[2 * e + 1]);
            if (ov < v3 || (ov == v3 && oi < i3)) {
                if (ov < v2 || (ov == v2 && oi < i2)) {
                    v3 = v2; i3 = i2;
                    if (ov < v1 || (ov == v1 && oi < i1)) {
                        v2 = v1; i2 = i1; v1 = ov; i1 = oi;
                    } else { v2 = ov; i2 = oi; }
                } else { v3 = ov; i3 = oi; }
            }
        }
        int row = blockIdx.x * 32 + tid;
        tok[row] = i1;
        out[2 * ZQ_ELEMS + (size_t)row] = (float)i1;
        if (v2 - v1 <= TAU_C) {
            if (v3 - v1 > TAU_C) {
                int p = atomicAdd(&cnt[0], 1) & (NROWS - 1);  // clamp: OOB-proof
                plist[p] = make_int4(row, i1, i2, 0);
            } else {
                int p = atomicAdd(&cnt[1], 1) & (NROWS - 1);  // clamp: OOB-proof
                flist[p] = row;
            }
        }
    }
}

// merged exact rescan.
// Phase A (pair items, one per wave, grid-strided): exact 2-candidate
// rescore, lanes split the 256-dim f64 dot, butterfly-reduce.
// Phase B (full items, one ROW per BLOCK): candidate-parallel — each of the
// 256 threads owns 4 consecutive emb rows and runs 4 interleaved f64 FMA
// chains; one f32 (val,idx) butterfly + 4-entry merge at the end. f64 dots,
// f32 outer emulation, first-index tie-break everywhere.
__global__ __launch_bounds__(256) void rescan2_kernel(const float* __restrict__ x,
                                                      const float* __restrict__ emb,
                                                      const float* __restrict__ esq,
                                                      const float* __restrict__ zsq,
                                                      int* __restrict__ tok,
                                                      const int4* __restrict__ plist,
                                                      const int* __restrict__ flist,
                                                      const int* __restrict__ cnt,
                                                      float* __restrict__ out) {
    __shared__ float zrow[A_DIM];
    __shared__ float wv[4];
    __shared__ int   wi[4];
    const int tid = threadIdx.x;
    const int w = tid >> 6, lane = tid & 63;

    // ---- phase A: pair items ----
    {
        const int nw = gridDim.x * 4;
        const int gw = blockIdx.x * 4 + w;
        const int np = min(cnt[0], NROWS);   // clamp: OOB-proof
        for (int i = gw; i < np; i += nw) {
            int4 e = plist[i];
            const int r = e.x, c1 = e.y, c2 = e.z;
            const float* xr = x + (size_t)(r >> 4) * 4096 + (r & 15);
            const float* e1 = emb + (size_t)c1 * A_DIM;
            const float* e2 = emb + (size_t)c2 * A_DIM;
            double d1 = 0.0, d2 = 0.0;
            #pragma unroll
            for (int k = 0; k < 4; ++k) {
                int a = lane + k * 64;
                double zv = (double)xr[a * 16];
                d1 = fma(zv, (double)e1[a], d1);
                d2 = fma(zv, (double)e2[a], d2);
            }
            #pragma unroll
            for (int m = 1; m < 64; m <<= 1) {
                d1 += __shfl_xor(d1, m);
                d2 += __shfl_xor(d2, m);
            }
            if (lane == 0) {
                float zq = zsq[r];
                float A1 = zq + esq[c1];
                float D1 = (float)(2.0 * d1);
                float s1 = A1 - D1;
                float A2 = zq + esq[c2];
                float D2 = (float)(2.0 * d2);
                float s2 = A2 - D2;
                int bi = (s2 < s1 || (s2 == s1 && c2 < c1)) ? c2 : c1;
                tok[r] = bi;
                out[2 * ZQ_ELEMS + (size_t)r] = (float)bi;
            }
        }
    }

    // ---- phase B: full rows, candidate-parallel ----
    const int nf = min(cnt[1], NROWS);       // clamp: OOB-proof
    for (int i = blockIdx.x; i < nf; i += gridDim.x) {
        const int r = flist[i];
        __syncthreads();   // previous iteration's zrow readers done
        zrow[tid] = x[(size_t)(r >> 4) * 4096 + (size_t)tid * 16 + (r & 15)];
        __syncthreads();

        // thread tid owns candidates 4*tid .. 4*tid+3 (contiguous emb rows)
        const float4* e0 = (const float4*)(emb + (size_t)tid * 4 * A_DIM);
        double d0 = 0.0, d1 = 0.0, d2 = 0.0, d3 = 0.0;
        #pragma unroll 8
        for (int k4 = 0; k4 < A_DIM / 4; ++k4) {
            float4 zf = *(const float4*)&zrow[k4 * 4];   // LDS broadcast
            double z0 = (double)zf.x, z1 = (double)zf.y;
            double z2 = (double)zf.z, z3 = (double)zf.w;
            float4 f0 = e0[k4];
            float4 f1 = e0[64 + k4];
            float4 f2 = e0[128 + k4];
            float4 f3 = e0[192 + k4];
            d0 = fma((double)f0.x, z0, d0); d0 = fma((double)f0.y, z1, d0);
            d0 = fma((double)f0.z, z2, d0); d0 = fma((double)f0.w, z3, d0);
            d1 = fma((double)f1.x, z0, d1); d1 = fma((double)f1.y, z1, d1);
            d1 = fma((double)f1.z, z2, d1); d1 = fma((double)f1.w, z3, d1);
            d2 = fma((double)f2.x, z0, d2); d2 = fma((double)f2.y, z1, d2);
            d2 = fma((double)f2.z, z2, d2); d2 = fma((double)f2.w, z3, d2);
            d3 = fma((double)f3.x, z0, d3); d3 = fma((double)f3.y, z1, d3);
            d3 = fma((double)f3.z, z2, d3); d3 = fma((double)f3.w, z3, d3);
        }
        const float zq = zsq[r];
        float bv = 3.0e38f; int bi = 0;
        double dd[4] = {d0, d1, d2, d3};
        #pragma unroll
        for (int cc = 0; cc < 4; ++cc) {               // ascending c
            int c = tid * 4 + cc;
            float A = zq + esq[c];                     // fl32(zsq + esq)
            float D = (float)(2.0 * dd[cc]);           // fl32(2*dot)
            float s = A - D;                           // fl32(A - D)
            if (s < bv) { bv = s; bi = c; }            // strict < -> first index
        }
        // wave butterfly on (bv,bi), explicit first-index tie-break
        #pragma unroll
        for (int m = 1; m < 64; m <<= 1) {
            float ov = __shfl_xor(bv, m); int oi = __shfl_xor(bi, m);
            if (ov < bv || (ov == bv && oi < bi)) { bv = ov; bi = oi; }
        }
        if (lane == 0) { wv[w] = bv; wi[w] = bi; }
        __syncthreads();
        if (tid == 0) {
            float BV = wv[0]; int BI = wi[0];
            #pragma unroll
            for (int t = 1; t < 4; ++t)
                if (wv[t] < BV || (wv[t] == BV && wi[t] < BI)) { BV = wv[t]; BI = wi[t]; }
            tok[r] = BI;
            out[2 * ZQ_ELEMS + (size_t)r] = (float)BI;
        }
    }
}

// gather epilogue: z_q + decoder_input
__global__ __launch_bounds__(256) void gather_kernel(const float* __restrict__ emb,
                                                     const int* __restrict__ tok,
                                                     float* __restrict__ out) {
    __shared__ int t16[16];
    const int tid = threadIdx.x;
    const int bl = blockIdx.x;
    if (tid < 16) t16[tid] = tok[bl * 16 + tid];
    __syncthreads();
    const int a = tid;
    __align__(16) float h[16];
    #pragma unroll
    for (int v = 0; v < 16; ++v) h[v] = emb[(size_t)t16[v] * A_DIM + a];
    size_t base = ((size_t)bl * A_DIM + a) * 16;
    float4* p0 = (float4*)(out + base);
    float4* p1 = (float4*)(out + ZQ_ELEMS + base);
    #pragma unroll
    for (int qq = 0; qq < 4; ++qq) {
        float4 val = *(float4*)&h[qq * 4];
        p0[qq] = val;
        p1[qq] = val;
    }
}

// ================= fallback path (round-5 PASSING kernel, verbatim) =================

__global__ __launch_bounds__(256) void prep_f(const float* __restrict__ emb,
                                              float* __restrict__ e_sq32) {
    int j = blockIdx.x * 256 + threadIdx.x;
    if (j < VOCAB) {
        const float4* row = (const float4*)(emb + (size_t)j * A_DIM);
        double s = 0.0;
        #pragma unroll 4
        for (int t = 0; t < A_DIM / 4; ++t) {
            float4 f = row[t];
            float sx = f.x * f.x, sy = f.y * f.y, sz = f.z * f.z, sw = f.w * f.w;
            s += (double)sx + (double)sy + (double)sz + (double)sw;
        }
        e_sq32[j] = (float)s;
    }
}

#define FBM 64
#define FBN 256
#define FBK 32
struct SmemF {
    union {
        struct { float zs[FBK][FBM]; float es[FBK][FBN]; };
        float4 mbuf[FBM][32];
        struct { double zrow[A_DIM]; float rbest[256]; int ridx[256]; };
    };
    double zsqp_s[4][FBM];
    float  zsq[FBM];
    int    tok[FBM];
    int    flagrows[FBM];
    int    nflag;
};

__global__ __launch_bounds__(256, 2) void main_f(const float* __restrict__ x,
                                                 const float* __restrict__ emb,
                                                 const float* __restrict__ e_sq32,
                                                 float* __restrict__ out) {
    __shared__ SmemF sm;
    const int tid = threadIdx.x;
    const int tx = tid & 31;
    const int ty = tid >> 5;
    const int blk = blockIdx.x;
    const int row0 = blk * FBM;
    const int bl0 = row0 >> 4;
    const int zrow_id = tid & 63;
    const int zq4     = tid >> 6;

    if (tid == 0) sm.nflag = 0;
    float v1[8], v2[8];
    int   i1[8], i2[8];
    #pragma unroll
    for (int r = 0; r < 8; ++r) { v1[r] = 3.0e38f; v2[r] = 3.0e38f; i1[r] = 0; i2[r] = 0; }
    double zsqp = 0.0;
    float4 zpf[2];
    float4 epf[8];
    for (int ct = 0; ct < VOCAB / FBN; ++ct) {
        float acc[8][8];
        #pragma unroll
        for (int rr = 0; rr < 8; ++rr)
            #pragma unroll
            for (int cc = 0; cc < 8; ++cc) acc[rr][cc] = 0.0f;
        for (int kt = 0; kt < A_DIM / FBK; ++kt) {
            if (kt == 0) {
                #pragma unroll
                for (int t = 0; t < 2; ++t) {
                    int f = tid + t * 256;
                    int v4 = f & 3, g = (f >> 2) & 3, kk = f >> 4;
                    zpf[t] = *(const float4*)(x + (size_t)(bl0 + g) * 4096 + (kt * FBK + kk) * 16 + v4 * 4);
                }
                #pragma unroll
                for (int t = 0; t < 8; ++t) {
                    int f = tid + t * 256;
                    int c = f & 255, k4 = f >> 8;
                    epf[t] = *(const float4*)(emb + (size_t)(ct * FBN + c) * A_DIM + kt * FBK + k4 * 4);
                }
            }
            __syncthreads();
            #pragma unroll
            for (int t = 0; t < 2; ++t) {
                int f = tid + t * 256;
                int v4 = f & 3, g = (f >> 2) & 3, kk = f >> 4;
                *(float4*)&sm.zs[kk][g * 16 + v4 * 4] = zpf[t];
            }
            #pragma unroll
            for (int t = 0; t < 8; ++t) {
                int f = tid + t * 256;
                int c = f & 255, k4 = f >> 8;
                sm.es[k4 * 4 + 0][c] = epf[t].x;
                sm.es[k4 * 4 + 1][c] = epf[t].y;
                sm.es[k4 * 4 + 2][c] = epf[t].z;
                sm.es[k4 * 4 + 3][c] = epf[t].w;
            }
            __syncthreads();
            if (kt + 1 < A_DIM / FBK) {
                #pragma unroll
                for (int t = 0; t < 2; ++t) {
                    int f = tid + t * 256;
                    int v4 = f & 3, g = (f >> 2) & 3, kk = f >> 4;
                    zpf[t] = *(const float4*)(x + (size_t)(bl0 + g) * 4096 + ((kt + 1) * FBK + kk) * 16 + v4 * 4);
                }
                #pragma unroll
                for (int t = 0; t < 8; ++t) {
                    int f = tid + t * 256;
                    int c = f & 255, k4 = f >> 8;
                    epf[t] = *(const float4*)(emb + (size_t)(ct * FBN + c) * A_DIM + (kt + 1) * FBK + k4 * 4);
                }
            }
            if (ct == 0 && (kt >> 1) == zq4) {
                #pragma unroll
                for (int kk = 0; kk < FBK; ++kk) {
                    float zf = sm.zs[kk][zrow_id];
                    float zf2 = zf * zf;
                    zsqp += (double)zf2;
                }
            }
            #pragma unroll 2
            for (int kk = 0; kk < FBK; ++kk) {
                float4 za = *(float4*)&sm.zs[kk][ty * 4];
                float4 zb = *(float4*)&sm.zs[kk][32 + ty * 4];
                float4 ea = *(float4*)&sm.es[kk][tx * 4];
                float4 eb = *(float4*)&sm.es[kk][128 + tx * 4];
                float zv[8] = {za.x, za.y, za.z, za.w, zb.x, zb.y, zb.z, zb.w};
                float ev[8] = {ea.x, ea.y, ea.z, ea.w, eb.x, eb.y, eb.z, eb.w};
                #pragma unroll
                for (int rr = 0; rr < 8; ++rr)
                    #pragma unroll
                    for (int cc = 0; cc < 8; ++cc)
                        acc[rr][cc] = fmaf(zv[rr], ev[cc], acc[rr][cc]);
            }
        }
        if (ct == 0) {
            sm.zsqp_s[zq4][zrow_id] = zsqp;
            __syncthreads();
            if (tid < FBM)
                sm.zsq[tid] = (float)(sm.zsqp_s[0][tid] + sm.zsqp_s[1][tid]
                                    + sm.zsqp_s[2][tid] + sm.zsqp_s[3][tid]);
            __syncthreads();
        }
        float esqv[8];
        #pragma unroll
        for (int cc = 0; cc < 8; ++cc) {
            int c = ct * FBN + (cc >> 2) * 128 + tx * 4 + (cc & 3);
            esqv[cc] = e_sq32[c];
        }
        #pragma unroll
        for (int rr = 0; rr < 8; ++rr) {
            int R = (rr >> 2) * 32 + ty * 4 + (rr & 3);
            float zq = sm.zsq[R];
            #pragma unroll
            for (int cc = 0; cc < 8; ++cc) {
                int c = ct * FBN + (cc >> 2) * 128 + tx * 4 + (cc & 3);
                float A = zq + esqv[cc];
                float s = fmaf(-2.0f, acc[rr][cc], A);
                if (s < v1[rr]) { v2[rr] = v1[rr]; i2[rr] = i1[rr]; v1[rr] = s; i1[rr] = c; }
                else if (s < v2[rr]) { v2[rr] = s; i2[rr] = c; }
            }
        }
    }
    __syncthreads();
    #pragma unroll
    for (int rr = 0; rr < 8; ++rr) {
        int r = (rr >> 2) * 32 + ty * 4 + (rr & 3);
        float4 m;
        m.x = v1[rr]; m.y = __int_as_float(i1[rr]);
        m.z = v2[rr]; m.w = __int_as_float(i2[rr]);
        sm.mbuf[r][tx] = m;
    }
    __syncthreads();
    if (tid < FBM) {
        int r = tid;
        float V1 = 3.0e38f, V2 = 3.0e38f;
        int I1 = 0, I2 = 0;
        for (int t = 0; t < 32; ++t) {
            float4 m = sm.mbuf[r][t];
            float a1 = m.x; int a1i = __float_as_int(m.y);
            float a2 = m.z; int a2i = __float_as_int(m.w);
            if (a1 < V1 || (a1 == V1 && a1i < I1)) { V2 = V1; I2 = I1; V1 = a1; I1 = a1i; }
            else if (a1 < V2 || (a1 == V2 && a1i < I2)) { V2 = a1; I2 = a1i; }
            if (a2 < V1 || (a2 == V1 && a2i < I1)) { V2 = V1; I2 = I1; V1 = a2; I1 = a2i; }
            else if (a2 < V2 || (a2 == V2 && a2i < I2)) { V2 = a2; I2 = a2i; }
        }
        sm.tok[r] = I1;
        if (V2 - V1 <= TAU_F) {
            int pos = atomicAdd(&sm.nflag, 1);
            sm.flagrows[pos] = r;
        }
    }
    __syncthreads();
    const int nf = sm.nflag;
    for (int i = 0; i < nf; ++i) {
        const int rl = sm.flagrows[i];
        const int bl = bl0 + (rl >> 4);
        const int v  = rl & 15;
        const float zqrow = sm.zsq[rl];
        sm.zrow[tid] = (double)x[(size_t)bl * 4096 + (size_t)tid * 16 + v];
        __syncthreads();
        float bv = 3.0e38f; int bi = 0;
        #pragma unroll
        for (int cc = 0; cc < 4; ++cc) {
            int c = tid * 4 + cc;
            const float4* er = (const float4*)(emb + (size_t)c * A_DIM);
            double dot = 0.0;
            #pragma unroll 8
            for (int k4 = 0; k4 < A_DIM / 4; ++k4) {
                float4 f = er[k4];
                dot = fma((double)f.x, sm.zrow[k4 * 4 + 0], dot);
                dot = fma((double)f.y, sm.zrow[k4 * 4 + 1], dot);
                dot = fma((double)f.z, sm.zrow[k4 * 4 + 2], dot);
                dot = fma((double)f.w, sm.zrow[k4 * 4 + 3], dot);
            }
            float A = zqrow + e_sq32[c];
            float D = (float)(2.0 * dot);
            float s = A - D;
            if (s < bv) { bv = s; bi = c; }
        }
        sm.rbest[tid] = bv; sm.ridx[tid] = bi;
        __syncthreads();
        if (tid == 0) {
            float BV = sm.rbest[0]; int BI = sm.ridx[0];
            for (int t = 1; t < 256; ++t) {
                float vv = sm.rbest[t];
                if (vv < BV) { BV = vv; BI = sm.ridx[t]; }
            }
            sm.tok[rl] = BI;
        }
        __syncthreads();
    }
    if (tid < FBM) {
        out[2 * ZQ_ELEMS + (size_t)(row0 + tid)] = (float)sm.tok[tid];
    }
    __syncthreads();
    const int a = tid;
    for (int g = 0; g < 4; ++g) {
        __align__(16) float h[16];
        #pragma unroll
        for (int v = 0; v < 16; ++v) {
            h[v] = emb[(size_t)sm.tok[g * 16 + v] * A_DIM + a];
        }
        size_t base = ((size_t)(bl0 + g) * A_DIM + a) * 16;
        float4* p0 = (float4*)(out + base);
        float4* p1 = (float4*)(out + ZQ_ELEMS + base);
        #pragma unroll
        for (int qq = 0; qq < 4; ++qq) {
            float4 val = *(float4*)&h[qq * 4];
            p0[qq] = val;
            p1[qq] = val;
        }
    }
}

extern "C" void kernel_launch(void* const* d_in, const int* in_sizes, int n_in,
                              void* d_out, int out_size, void* d_ws, size_t ws_size,
                              hipStream_t stream) {
    (void)in_sizes; (void)n_in; (void)out_size;
    const float* x   = (const float*)d_in[0];
    const float* emb = (const float*)d_in[1];
    float* out = (float*)d_out;
    char* ws = (char*)d_ws;

    if (ws_size >= WS_NEED) {
        _Float16* eht = (_Float16*)(ws + WS_EHT);
        _Float16* zh  = (_Float16*)(ws + WS_ZH);
        float* esq    = (float*)(ws + WS_ESQ);
        float* zsq    = (float*)(ws + WS_ZSQ);
        int* tok      = (int*)(ws + WS_TOK);
        int4* plist   = (int4*)(ws + WS_PLIST);
        int* flist    = (int*)(ws + WS_FLIST);
        int* cnt      = (int*)(ws + WS_CNT);

        prep_e_kernel<<<64, 256, 0, stream>>>(emb, esq, eht, cnt);
        prep_z_kernel<<<2048, 256, 0, stream>>>(x, zh, zsq);
        mfma_kernel<<<1024, 256, 0, stream>>>(zh, eht, esq, tok, plist, flist, cnt, out);
        rescan2_kernel<<<256, 256, 0, stream>>>(x, emb, esq, zsq, tok, plist, flist, cnt, out);
        gather_kernel<<<2048, 256, 0, stream>>>(emb, tok, out);
    } else {
        float* e_sq32 = (float*)ws;
        prep_f<<<4, 256, 0, stream>>>(emb, e_sq32);
        main_f<<<512, 256, 0, stream>>>(x, emb, e_sq32, out);
    }
}